// Round 1
// 870.875 us; speedup vs baseline: 1.0304x; 1.0304x over previous
//
#include <hip/hip_runtime.h>

typedef unsigned short u16;
typedef unsigned int u32;
typedef float f32x4 __attribute__((ext_vector_type(4)));
typedef __bf16 bf16x8 __attribute__((ext_vector_type(8)));

#define NTOK 8192
#define HDIM 1024
#define FFDIM 4096
#define NEXP 8
#define CAP 1024

typedef const __attribute__((address_space(1))) void gvoid_t;
typedef __attribute__((address_space(3))) void lvoid_t;

__device__ __forceinline__ u16 f2bf(float f) {
  u32 u = __float_as_uint(f);
  u += 0x7fffu + ((u >> 16) & 1u);
  return (u16)(u >> 16);
}

// tanh-approx gelu (matches jax.nn.gelu approximate=True)
__device__ __forceinline__ float gelu_f(float x) {
  float u = 1.5957691216057308f * (x + 0.044715f * x * x * x);
  return x / (1.0f + __expf(-u));
}

// ---------------- fp32 -> bf16 convert (vectorized) ----------------
__global__ __launch_bounds__(256) void convert_bf16(const float* __restrict__ src,
                                                    u16* __restrict__ dst,
                                                    long long n) {
  long long i = ((long long)blockIdx.x * 256 + threadIdx.x) * 8;
  if (i >= n) return;
  float4 f0 = *(const float4*)(src + i);
  float4 f1 = *(const float4*)(src + i + 4);
  union { u16 u[8]; uint4 v; } o;
  o.u[0] = f2bf(f0.x); o.u[1] = f2bf(f0.y); o.u[2] = f2bf(f0.z); o.u[3] = f2bf(f0.w);
  o.u[4] = f2bf(f1.x); o.u[5] = f2bf(f1.y); o.u[6] = f2bf(f1.z); o.u[7] = f2bf(f1.w);
  *(uint4*)(dst + i) = o.v;
}

// ---------------- transpose fp32 [R][C] -> bf16 [C][R] ----------------
__global__ __launch_bounds__(256) void transpose_f32_bf16(const float* __restrict__ src,
                                                          long long sBatch,
                                                          u16* __restrict__ dst,
                                                          long long dBatch,
                                                          int R, int C) {
  __shared__ float tile[32][33];
  int z = blockIdx.z;
  const float* s = src + (long long)z * sBatch;
  u16* d = dst + (long long)z * dBatch;
  int c0 = blockIdx.x * 32, r0 = blockIdx.y * 32;
  int tx = threadIdx.x, ty = threadIdx.y;  // (32, 8)
#pragma unroll
  for (int i = 0; i < 32; i += 8)
    tile[ty + i][tx] = s[(long long)(r0 + ty + i) * C + c0 + tx];
  __syncthreads();
#pragma unroll
  for (int i = 0; i < 32; i += 8)
    d[(long long)(c0 + ty + i) * R + r0 + tx] = f2bf(tile[tx][ty + i]);
}

// ---------------- gating: one wave per token, no atomics ----------------
__global__ __launch_bounds__(256) void gate_kernel(const float* __restrict__ x,
                                                   const float* __restrict__ wg,
                                                   const float* __restrict__ cw,
                                                   const float* __restrict__ cb,
                                                   int* __restrict__ idx1,
                                                   float* __restrict__ gate_val,
                                                   float* __restrict__ gates8,
                                                   float* __restrict__ coef) {
  const int wave = threadIdx.x >> 6, lane = threadIdx.x & 63;
  const int s = blockIdx.x * 4 + wave;
  const float* xr = x + (long long)s * HDIM;
  double p[10];
#pragma unroll
  for (int v = 0; v < 10; ++v) p[v] = 0.0;
#pragma unroll 4
  for (int i = 0; i < HDIM / 64; ++i) {
    int hh = i * 64 + lane;
    float xv = xr[hh];
    float4 w0 = *(const float4*)(wg + hh * 8);
    float4 w1 = *(const float4*)(wg + hh * 8 + 4);
    float2 c = *(const float2*)(cw + hh * 2);
    double xd = (double)xv;
    p[0] += xd * (double)w0.x; p[1] += xd * (double)w0.y;
    p[2] += xd * (double)w0.z; p[3] += xd * (double)w0.w;
    p[4] += xd * (double)w1.x; p[5] += xd * (double)w1.y;
    p[6] += xd * (double)w1.z; p[7] += xd * (double)w1.w;
    p[8] += xd * (double)c.x;  p[9] += xd * (double)c.y;
  }
#pragma unroll
  for (int v = 0; v < 10; ++v)
#pragma unroll
    for (int off = 32; off > 0; off >>= 1) p[v] += __shfl_down(p[v], off);
  if (lane == 0) {
    double mx = p[0]; int am = 0;
#pragma unroll
    for (int e = 1; e < 8; ++e)
      if (p[e] > mx) { mx = p[e]; am = e; }
    float g[8]; float sum = 0.f;
#pragma unroll
    for (int e = 0; e < 8; ++e) { g[e] = __expf((float)(p[e] - mx)); sum += g[e]; }
    float inv = 1.f / sum;
#pragma unroll
    for (int e = 0; e < 8; ++e) { g[e] *= inv; gates8[s * 8 + e] = g[e]; }
    idx1[s] = am;
    gate_val[s] = g[am];
    float c0 = (float)p[8] + cb[0], c1 = (float)p[9] + cb[1];
    float m2 = fmaxf(c0, c1);
    float e0 = __expf(c0 - m2), e1 = __expf(c1 - m2);
    float is = 1.f / (e0 + e1);
    coef[2 * s] = e0 * is;
    coef[2 * s + 1] = e1 * is;
  }
}

// ---------------- in-order cumsum scan: slot assignment + l_aux + counts ----------------
__global__ void scan_kernel(const int* __restrict__ idx1,
                            const float* __restrict__ gates8,
                            int* __restrict__ rowmap,     // [E][CAP] pre-filled -1
                            float* __restrict__ out_tail) // [l_aux, exp_counts x8]
{
  int lane = threadIdx.x;  // 64 threads, 1 block
  int cnt[8];
  float me[8];
#pragma unroll
  for (int e = 0; e < 8; ++e) { cnt[e] = 0; me[e] = 0.f; }
  unsigned long long below = (lane == 0) ? 0ull : ((~0ull) >> (64 - lane));
  int eN = idx1[lane];
  float4 gN0 = *(const float4*)(gates8 + lane * 8);
  float4 gN1 = *(const float4*)(gates8 + lane * 8 + 4);
  for (int it = 0; it < NTOK / 64; ++it) {
    int tok = it * 64 + lane;
    int e = eN;
    float4 g0 = gN0, g1 = gN1;
    if (it + 1 < NTOK / 64) {
      eN = idx1[tok + 64];
      gN0 = *(const float4*)(gates8 + (tok + 64) * 8);
      gN1 = *(const float4*)(gates8 + (tok + 64) * 8 + 4);
    }
    me[0] += g0.x; me[1] += g0.y; me[2] += g0.z; me[3] += g0.w;
    me[4] += g1.x; me[5] += g1.y; me[6] += g1.z; me[7] += g1.w;
#pragma unroll
    for (int xx = 0; xx < 8; ++xx) {
      unsigned long long m = __ballot(e == xx);
      if (e == xx) {
        int pos = cnt[xx] + __popcll(m & below);
        if (pos < CAP) rowmap[xx * CAP + pos] = tok;
      }
      cnt[xx] += __popcll(m);
    }
  }
#pragma unroll
  for (int xx = 0; xx < 8; ++xx)
#pragma unroll
    for (int off = 32; off > 0; off >>= 1) me[xx] += __shfl_down(me[xx], off);
  if (lane == 0) {
    float laux = 0.f;
#pragma unroll
    for (int e = 0; e < 8; ++e) {
      out_tail[1 + e] = (float)cnt[e];
      laux += (me[e] / (float)NTOK) * ((float)cnt[e] / (float)NTOK);
    }
    out_tail[0] = laux * (float)NEXP;
  }
}

// =====================================================================
// 256-wide-N bf16 MFMA GEMM, BK=64, 512 threads (8 waves, 2M x 4N),
// phase-interleaved schedule with counted vmcnt (never 0 in main loop).
//
// Tile: BM x 256 (BM = 256 for FFN1 shapes, 128 for the N=1024 FFN2
// shapes so the grid stays >= 256 workgroups at 1 block/CU).
// LDS: double-buffered A (BM x 64) + B (256 x 64), XOR-swizzled 16B
// k-chunks exactly as the proven gemm128: LDS slot s of row r holds
// global k-chunk s^(r&7); source address is pre-swizzled, LDS linear.
//
// Halves: A-half qa = rows [qa*BM/2, ...), B-half qb = Bt rows
// [qb*128, ...). Per K-tile, 4 phases = quadrants (qa,qb) in order
// (0,0),(0,1),(1,0),(1,1). Wave (wr = w>>2, wc = w&3) computes rows
// qa*BM/2 + wr*BM/4 + [0,BM/4), cols qb*128 + wc*32 + [0,32), so each
// phase collectively touches exactly A-half qa and B-half qb.
//
// Staging of tile T+1 during tile T (into the other buffer):
//   P1: A0 + B0   P2: B1   P3: A1   P4: -
// Half staged at tile T phase k is first read at tile T+1 phase k' and
// guaranteed landed by a counted vmcnt at the end of the preceding
// phase + s_barrier (per-wave vmcnt before a barrier => collective
// guarantee after it):
//   P1-end vmcnt(6|4): forces B1(T)   (needed P2)
//   P2-end vmcnt(6|5): forces A1(T)   (needed P3)
//   P3-end: no wait                   (P4 reads nothing new)
//   P4-end vmcnt(4|3): forces A0,B0(T+1) (needed T+1.P1)
// (second number = BM=128 variant: A-halves are 1 load/thread there)
// Last tile: no stages, vmcnt(0) at those points (drains everything).
// =====================================================================

#define GLDS(gp, lp) __builtin_amdgcn_global_load_lds((gvoid_t*)(gp), (lvoid_t*)(lp), 16, 0, 0)
#define WAITV(n) asm volatile("s_waitcnt vmcnt(" #n ")" ::: "memory")
#define MFMA16(a, b, c) __builtin_amdgcn_mfma_f32_16x16x32_bf16(a, b, c, 0, 0, 0)
#define SBAR() __builtin_amdgcn_s_barrier()

template <int BM>
__global__ __launch_bounds__(512, 2) void gemm256(
    const u16* __restrict__ Aall, long long aBatch,
    const u16* __restrict__ Ball, long long bBatch,
    int M, int N, int K,
    const int* __restrict__ amapAll,  // nullptr or [Z][M] token-row map (-1 = empty)
    int mode,                         // 0: h=gelu(A@B)  1: moe scatter  2: final blend
    u16* __restrict__ hOut, long long hBatch,
    const int* __restrict__ rmapAll,
    const float* __restrict__ gate_val,
    float* __restrict__ moe_acc,
    const float* __restrict__ coef,
    float* __restrict__ outf) {
  constexpr int MF = BM / 64;   // M-frags per phase (4 or 2)
  constexpr int NGA = BM / 64;  // A 64-row stage groups (4 or 2)
  const int z = blockIdx.z;
  const u16* A = Aall + (long long)z * aBatch;
  const u16* Bt = Ball + (long long)z * bBatch;
  const int tid = threadIdx.x;
  const int lane = tid & 63;
  const int wv = tid >> 6;
  const int wv8 = wv * 8;
  const int wr = wv >> 2, wc = wv & 3;
  const int tileM = blockIdx.y * BM;
  const int tileN = blockIdx.x * 256;

  __shared__ __align__(16) u16 As[2][BM * 64];
  __shared__ __align__(16) u16 Bs[2][256 * 64];

  // staging: thread t covers row (t>>3) of each 64-row group, LDS 16B slot
  // t&7; swizzled global source chunk = (t&7)^(row&7)
  const int srow = tid >> 3;  // 0..63
  const int gkS = (((tid & 7) ^ (srow & 7)) << 3);
  const u16* aP[NGA];
  const u16* bP[4];
  if (amapAll) {
    const int* amap = amapAll + (long long)z * M;
#pragma unroll
    for (int g = 0; g < NGA; ++g) {
      int s0 = amap[tileM + g * 64 + srow];
      aP[g] = A + (long long)(s0 < 0 ? 0 : s0) * K + gkS;
    }
  } else {
#pragma unroll
    for (int g = 0; g < NGA; ++g)
      aP[g] = A + (long long)(tileM + g * 64 + srow) * K + gkS;
  }
#pragma unroll
  for (int g = 0; g < 4; ++g)
    bP[g] = Bt + (long long)(tileN + g * 64 + srow) * K + gkS;

#define STAGE_A(nb, h)                                                    \
  {                                                                       \
    if constexpr (BM == 256) {                                            \
      GLDS(aP[2 * (h)], &As[nb][((2 * (h)) * 64 + wv8) * 64]);            \
      GLDS(aP[2 * (h) + 1], &As[nb][((2 * (h) + 1) * 64 + wv8) * 64]);    \
      aP[2 * (h)] += 64;                                                  \
      aP[2 * (h) + 1] += 64;                                              \
    } else {                                                              \
      GLDS(aP[(h)], &As[nb][((h) * 64 + wv8) * 64]);                      \
      aP[(h)] += 64;                                                      \
    }                                                                     \
  }
#define STAGE_B(nb, h)                                                    \
  {                                                                       \
    GLDS(bP[2 * (h)], &Bs[nb][((2 * (h)) * 64 + wv8) * 64]);              \
    GLDS(bP[2 * (h) + 1], &Bs[nb][((2 * (h) + 1) * 64 + wv8) * 64]);      \
    bP[2 * (h)] += 64;                                                    \
    bP[2 * (h) + 1] += 64;                                                \
  }

  // prologue: stage tile 0 into buffer 0, issue order A0,B0,B1,A1.
  STAGE_A(0, 0);
  STAGE_B(0, 0);
  STAGE_B(0, 1);
  STAGE_A(0, 1);
  // force A0,B0 landed (leave B1,A1 in flight), then barrier.
  if constexpr (BM == 256) { WAITV(4); } else { WAITV(3); }
  SBAR();

  // fragment read addressing: row r (stride 64 elem), chunk c at LDS slot
  // c^(r&7); frag rows are +rlo off multiples of 16 so r&7 == rlo&7.
  const int rlo = lane & 15, kq = lane >> 4;
  const int sw = rlo & 7;
  const int ksA = ((kq ^ sw) << 3);        // k-sub 0 (k = kq*8)
  const int ksB = (((4 | kq) ^ sw) << 3);  // k-sub 1 (k = 32 + kq*8)
  int aBase[2], bBase[2];
#pragma unroll
  for (int qa = 0; qa < 2; ++qa)
    aBase[qa] = (qa * (BM / 2) + wr * (BM / 4) + rlo) * 64;
#pragma unroll
  for (int qb = 0; qb < 2; ++qb)
    bBase[qb] = (qb * 128 + wc * 32 + rlo) * 64;

  f32x4 acc[2 * MF][4];
  const f32x4 fz = {0.f, 0.f, 0.f, 0.f};
#pragma unroll
  for (int i = 0; i < 2 * MF; ++i)
#pragma unroll
    for (int j = 0; j < 4; ++j) acc[i][j] = fz;

  const int NT = K / 64;
  for (int T = 0; T < NT; ++T) {
    const int p = T & 1, nb = p ^ 1;
    const bool pre = (T + 1 < NT);
    const u16* Ap = As[p];
    const u16* Bp = Bs[p];
    bf16x8 af[MF][2], bfr[2][2];

    // ---- phase 1: quadrant (0,0); stage A0+B0 of next tile ----
#pragma unroll
    for (int i = 0; i < MF; ++i) {
      af[i][0] = *(const bf16x8*)&Ap[aBase[0] + i * 1024 + ksA];
      af[i][1] = *(const bf16x8*)&Ap[aBase[0] + i * 1024 + ksB];
    }
#pragma unroll
    for (int j = 0; j < 2; ++j) {
      bfr[j][0] = *(const bf16x8*)&Bp[bBase[0] + j * 1024 + ksA];
      bfr[j][1] = *(const bf16x8*)&Bp[bBase[0] + j * 1024 + ksB];
    }
    if (pre) { STAGE_A(nb, 0); STAGE_B(nb, 0); }
    SBAR();
    __builtin_amdgcn_s_setprio(1);
#pragma unroll
    for (int i = 0; i < MF; ++i)
#pragma unroll
      for (int j = 0; j < 2; ++j) {
        f32x4 c = acc[i][j];
        c = MFMA16(af[i][0], bfr[j][0], c);
        c = MFMA16(af[i][1], bfr[j][1], c);
        acc[i][j] = c;
      }
    __builtin_amdgcn_s_setprio(0);
    if (pre) {
      if constexpr (BM == 256) { WAITV(6); } else { WAITV(4); }
    } else { WAITV(0); }
    SBAR();

    // ---- phase 2: quadrant (0,1), A reused; stage B1 ----
#pragma unroll
    for (int j = 0; j < 2; ++j) {
      bfr[j][0] = *(const bf16x8*)&Bp[bBase[1] + j * 1024 + ksA];
      bfr[j][1] = *(const bf16x8*)&Bp[bBase[1] + j * 1024 + ksB];
    }
    if (pre) { STAGE_B(nb, 1); }
    SBAR();
    __builtin_amdgcn_s_setprio(1);
#pragma unroll
    for (int i = 0; i < MF; ++i)
#pragma unroll
      for (int j = 0; j < 2; ++j) {
        f32x4 c = acc[i][2 + j];
        c = MFMA16(af[i][0], bfr[j][0], c);
        c = MFMA16(af[i][1], bfr[j][1], c);
        acc[i][2 + j] = c;
      }
    __builtin_amdgcn_s_setprio(0);
    if (pre) {
      if constexpr (BM == 256) { WAITV(6); } else { WAITV(5); }
    } else { WAITV(0); }
    SBAR();

    // ---- phase 3: quadrant (1,0); stage A1 ----
#pragma unroll
    for (int i = 0; i < MF; ++i) {
      af[i][0] = *(const bf16x8*)&Ap[aBase[1] + i * 1024 + ksA];
      af[i][1] = *(const bf16x8*)&Ap[aBase[1] + i * 1024 + ksB];
    }
#pragma unroll
    for (int j = 0; j < 2; ++j) {
      bfr[j][0] = *(const bf16x8*)&Bp[bBase[0] + j * 1024 + ksA];
      bfr[j][1] = *(const bf16x8*)&Bp[bBase[0] + j * 1024 + ksB];
    }
    if (pre) { STAGE_A(nb, 1); }
    SBAR();
    __builtin_amdgcn_s_setprio(1);
#pragma unroll
    for (int i = 0; i < MF; ++i)
#pragma unroll
      for (int j = 0; j < 2; ++j) {
        f32x4 c = acc[MF + i][j];
        c = MFMA16(af[i][0], bfr[j][0], c);
        c = MFMA16(af[i][1], bfr[j][1], c);
        acc[MF + i][j] = c;
      }
    __builtin_amdgcn_s_setprio(0);
    SBAR();  // no vmcnt needed: phase 4 reads nothing newly staged

    // ---- phase 4: quadrant (1,1), A reused; no stage ----
#pragma unroll
    for (int j = 0; j < 2; ++j) {
      bfr[j][0] = *(const bf16x8*)&Bp[bBase[1] + j * 1024 + ksA];
      bfr[j][1] = *(const bf16x8*)&Bp[bBase[1] + j * 1024 + ksB];
    }
    SBAR();
    __builtin_amdgcn_s_setprio(1);
#pragma unroll
    for (int i = 0; i < MF; ++i)
#pragma unroll
      for (int j = 0; j < 2; ++j) {
        f32x4 c = acc[MF + i][2 + j];
        c = MFMA16(af[i][0], bfr[j][0], c);
        c = MFMA16(af[i][1], bfr[j][1], c);
        acc[MF + i][2 + j] = c;
      }
    __builtin_amdgcn_s_setprio(0);
    if (pre) {
      if constexpr (BM == 256) { WAITV(4); } else { WAITV(3); }
    } else { WAITV(0); }
    SBAR();
  }

  // epilogue: D row = (lane>>4)*4 + reg, col = lane&15 within each 16x16 tile
  const int qr = (lane >> 4) * 4;
  const int cc = lane & 15;
  if (mode == 0) {
    u16* hO = hOut + (long long)z * hBatch;
#pragma unroll
    for (int qa = 0; qa < 2; ++qa)
#pragma unroll
      for (int i = 0; i < MF; ++i) {
        int rbase = tileM + qa * (BM / 2) + wr * (BM / 4) + i * 16 + qr;
#pragma unroll
        for (int qb = 0; qb < 2; ++qb)
#pragma unroll
          for (int j = 0; j < 2; ++j) {
            int col = tileN + qb * 128 + wc * 32 + j * 16 + cc;
#pragma unroll
            for (int r = 0; r < 4; ++r)
              hO[(long long)(rbase + r) * N + col] =
                  f2bf(gelu_f(acc[qa * MF + i][qb * 2 + j][r]));
          }
      }
  } else if (mode == 1) {
    const int* rmap = rmapAll + (long long)z * M;
#pragma unroll
    for (int qa = 0; qa < 2; ++qa)
#pragma unroll
      for (int i = 0; i < MF; ++i) {
        int rbase = tileM + qa * (BM / 2) + wr * (BM / 4) + i * 16 + qr;
#pragma unroll
        for (int qb = 0; qb < 2; ++qb)
#pragma unroll
          for (int j = 0; j < 2; ++j) {
            int col = tileN + qb * 128 + wc * 32 + j * 16 + cc;
#pragma unroll
            for (int r = 0; r < 4; ++r) {
              int s = rmap[rbase + r];
              if (s >= 0)
                moe_acc[(long long)s * HDIM + col] =
                    gate_val[s] * acc[qa * MF + i][qb * 2 + j][r];
            }
          }
      }
  } else {
#pragma unroll
    for (int qa = 0; qa < 2; ++qa)
#pragma unroll
      for (int i = 0; i < MF; ++i) {
        int rbase = tileM + qa * (BM / 2) + wr * (BM / 4) + i * 16 + qr;
#pragma unroll
        for (int qb = 0; qb < 2; ++qb)
#pragma unroll
          for (int j = 0; j < 2; ++j) {
            int col = tileN + qb * 128 + wc * 32 + j * 16 + cc;
#pragma unroll
            for (int r = 0; r < 4; ++r) {
              int s = rbase + r;
              outf[(long long)s * HDIM + col] =
                  coef[2 * s] * moe_acc[(long long)s * HDIM + col] +
                  coef[2 * s + 1] * acc[qa * MF + i][qb * 2 + j][r];
            }
          }
      }
  }
}
#undef STAGE_A
#undef STAGE_B

extern "C" void kernel_launch(void* const* d_in, const int* in_sizes, int n_in,
                              void* d_out, int out_size, void* d_ws, size_t ws_size,
                              hipStream_t stream) {
  (void)in_sizes; (void)n_in; (void)out_size; (void)ws_size;
  const float* x   = (const float*)d_in[0];
  const float* wg  = (const float*)d_in[1];
  const float* w1  = (const float*)d_in[2];
  const float* w2  = (const float*)d_in[3];
  const float* rw1 = (const float*)d_in[4];
  const float* rw2 = (const float*)d_in[5];
  const float* cw  = (const float*)d_in[6];
  const float* cb  = (const float*)d_in[7];
  float* out = (float*)d_out;

  char* ws = (char*)d_ws;
  constexpr size_t OFF_XB   = 0;
  constexpr size_t OFF_W1T  = OFF_XB  + (size_t)NTOK * HDIM * 2;
  constexpr size_t OFF_W2T  = OFF_W1T + (size_t)NEXP * FFDIM * HDIM * 2;
  constexpr size_t OFF_H    = OFF_W2T + (size_t)NEXP * HDIM * FFDIM * 2;
  constexpr size_t OFF_MOE  = OFF_H   + (size_t)NEXP * CAP * FFDIM * 2;
  constexpr size_t OFF_GATE = OFF_MOE + (size_t)NTOK * HDIM * 4;
  constexpr size_t OFF_COEF = OFF_GATE + (size_t)NTOK * 4;
  constexpr size_t OFF_IDX  = OFF_COEF + (size_t)NTOK * 8;
  constexpr size_t OFF_RMAP = OFF_IDX + (size_t)NTOK * 4;
  constexpr size_t OFF_G8   = OFF_RMAP + (size_t)NEXP * CAP * 4;

  u16* xb        = (u16*)(ws + OFF_XB);
  u16* w1t       = (u16*)(ws + OFF_W1T);
  u16* w2t       = (u16*)(ws + OFF_W2T);
  u16* h         = (u16*)(ws + OFF_H);
  float* moe_acc = (float*)(ws + OFF_MOE);
  float* gate_v  = (float*)(ws + OFF_GATE);
  float* coef    = (float*)(ws + OFF_COEF);
  int* idx1      = (int*)(ws + OFF_IDX);
  int* rowmap    = (int*)(ws + OFF_RMAP);
  float* gates8  = (float*)(ws + OFF_G8);

  hipMemsetAsync(rowmap, 0xFF, (size_t)NEXP * CAP * 4, stream);
  hipMemsetAsync(moe_acc, 0, (size_t)NTOK * HDIM * 4, stream);

  convert_bf16<<<4096, 256, 0, stream>>>(x, xb, (long long)NTOK * HDIM);
  gate_kernel<<<NTOK / 4, 256, 0, stream>>>(x, wg, cw, cb, idx1, gate_v, gates8, coef);
  scan_kernel<<<1, 64, 0, stream>>>(idx1, gates8, rowmap, out + (size_t)NTOK * HDIM);

  // weight transposes: w1[e] [H][FF] -> w1t[e] [FF][H]; w2[e] [FF][H] -> w2t[e] [H][FF]
  transpose_f32_bf16<<<dim3(FFDIM / 32, HDIM / 32, NEXP), dim3(32, 8), 0, stream>>>(
      w1, (long long)HDIM * FFDIM, w1t, (long long)FFDIM * HDIM, HDIM, FFDIM);
  transpose_f32_bf16<<<dim3(HDIM / 32, FFDIM / 32, NEXP), dim3(32, 8), 0, stream>>>(
      w2, (long long)FFDIM * HDIM, w2t, (long long)HDIM * FFDIM, FFDIM, HDIM);

  // expert FFN1: h[e] = gelu(gather(xb, rowmap[e]) @ w1[e])   [CAP x FF]
  gemm256<256><<<dim3(FFDIM / 256, CAP / 256, NEXP), 512, 0, stream>>>(
      xb, 0, w1t, (long long)FFDIM * HDIM, CAP, FFDIM, HDIM,
      rowmap, 0, h, (long long)CAP * FFDIM, nullptr, nullptr, nullptr, nullptr, nullptr);
  // expert FFN2 + scatter: moe_acc[token] = gate * (h[e] @ w2[e])
  gemm256<128><<<dim3(HDIM / 256, CAP / 128, NEXP), 512, 0, stream>>>(
      h, (long long)CAP * FFDIM, w2t, (long long)HDIM * FFDIM, CAP, HDIM, FFDIM,
      nullptr, 1, nullptr, 0, rowmap, gate_v, moe_acc, nullptr, nullptr);

  // residual weights reuse the w1t/w2t regions
  transpose_f32_bf16<<<dim3(FFDIM / 32, HDIM / 32, 1), dim3(32, 8), 0, stream>>>(
      rw1, 0, w1t, 0, HDIM, FFDIM);
  transpose_f32_bf16<<<dim3(HDIM / 32, FFDIM / 32, 1), dim3(32, 8), 0, stream>>>(
      rw2, 0, w2t, 0, FFDIM, HDIM);

  // residual FFN1: h = gelu(xb @ res_w1)   [NTOK x FF]
  gemm256<256><<<dim3(FFDIM / 256, NTOK / 256, 1), 512, 0, stream>>>(
      xb, 0, w1t, 0, NTOK, FFDIM, HDIM,
      nullptr, 0, h, 0, nullptr, nullptr, nullptr, nullptr, nullptr);
  // residual FFN2 + final blend: out = c0*moe_acc + c1*(h @ res_w2)
  gemm256<128><<<dim3(HDIM / 256, NTOK / 128, 1), 512, 0, stream>>>(
      h, 0, w2t, 0, NTOK, HDIM, FFDIM,
      nullptr, 2, nullptr, 0, nullptr, nullptr, moe_acc, coef, out);
}